// Round 10
// baseline (188.253 us; speedup 1.0000x reference)
//
#include <hip/hip_runtime.h>
#include <hip/hip_fp16.h>
#include <stdint.h>

typedef float f4 __attribute__((ext_vector_type(4)));
typedef float f32x4 __attribute__((ext_vector_type(4)));
typedef _Float16 f16x8 __attribute__((ext_vector_type(8)));

#define BSHIFT 8
#define BMASK  255
#define BCAP   8192   // edges per 256-node bucket (mean 4096 -> huge headroom)

// ---------- prep: zero gcur + transpose W1/W2 -> fp16 [c][k] (replaces memset) ----------
__global__ __launch_bounds__(256) void prep_kernel(const float* __restrict__ W1,
                                                   const float* __restrict__ W2,
                                                   __half* __restrict__ Wt1,
                                                   __half* __restrict__ Wt2,
                                                   int* __restrict__ gcur) {
    int t = threadIdx.x, b = blockIdx.x;
    if (b == 0) { gcur[t] = 0; return; }
    int wi = (b - 1) >> 3, bi = (b - 1) & 7;
    const f4* w4 = (const f4*)(wi ? W2 : W1);
    _Float16* dst = (_Float16*)(wi ? Wt2 : Wt1);
#pragma unroll
    for (int it = 0; it < 2; ++it) {
        int chunk = bi * 512 + it * 256 + t;      // f4 index into 128x128 W
        f4 v = w4[chunk];
        int k = chunk >> 5, c0 = (chunk << 2) & 127;
#pragma unroll
        for (int u = 0; u < 4; ++u)
            dst[(size_t)(c0 + u) * 128 + k] = (_Float16)v[u];
    }
}

// ---------- stage B (Wt fp16 [c][k]) into swizzled LDS: byte^=((c&7)<<4) ----------
__device__ __forceinline__ void stage_B(_Float16* Bsw, const __half* __restrict__ Wt) {
    int t = threadIdx.x;
    const f4* wsrc = (const f4*)Wt;
#pragma unroll
    for (int i = 0; i < 8; ++i) {
        int cb = i * 256 + t;
        f4 v = wsrc[cb];
        int lin = cb * 16;
        int c = cb >> 4;
        *(f4*)((char*)Bsw + (lin ^ ((c & 7) << 4))) = v;
    }
}

// ---------- gemm1 body: g1c[row] = half(x_f32[row] @ W); A in regs (hi+lo fp16) ----------
__device__ __forceinline__ void gemm1_body(char* smem, int blk,
                                           const float* __restrict__ src,
                                           const __half* __restrict__ Wt,
                                           __half* __restrict__ g16, int nrows) {
    _Float16* Bsw = (_Float16*)smem;   // 32 KB
    stage_B(Bsw, Wt);

    int t = threadIdx.x;
    int w = t >> 6, lane = t & 63;
    int li = lane & 15, hg = lane >> 4;
    int r = blk * 64 + w * 16 + li;
    int rc = r < nrows ? r : nrows - 1;
    const float* xr = src + (size_t)rc * 128;

    f16x8 af[4], al[4];
#pragma unroll
    for (int kk = 0; kk < 4; ++kk) {
        f4 v0 = *(const f4*)(xr + kk * 32 + hg * 8);
        f4 v1 = *(const f4*)(xr + kk * 32 + hg * 8 + 4);
#pragma unroll
        for (int u = 0; u < 4; ++u) {
            float a0 = v0[u]; _Float16 h0 = (_Float16)a0;
            af[kk][u] = h0;     al[kk][u]     = (_Float16)(a0 - (float)h0);
            float a1 = v1[u]; _Float16 h1 = (_Float16)a1;
            af[kk][u + 4] = h1; al[kk][u + 4] = (_Float16)(a1 - (float)h1);
        }
    }
    __syncthreads();   // B ready (A loads overlapped with B staging)

    f32x4 acc[8];
#pragma unroll
    for (int nn = 0; nn < 8; ++nn) acc[nn] = (f32x4)0.0f;
#pragma unroll
    for (int nn = 0; nn < 8; ++nn) {
        int c = nn * 16 + li;
        int cbase = c * 256;
        int sw = (c & 7) << 4;
#pragma unroll
        for (int kk = 0; kk < 4; ++kk) {
            f16x8 bf = *(const f16x8*)((const char*)Bsw + ((cbase + kk * 64 + hg * 16) ^ sw));
            acc[nn] = __builtin_amdgcn_mfma_f32_16x16x32_f16(af[kk], bf, acc[nn], 0, 0, 0);
            acc[nn] = __builtin_amdgcn_mfma_f32_16x16x32_f16(al[kk], bf, acc[nn], 0, 0, 0);
        }
    }

    // epilogue: C/D col = lane&15, row = (lane>>4)*4 + reg (m89); COMPACT 256-B rows
    int gr0 = blk * 64 + w * 16 + (hg << 2);
#pragma unroll
    for (int nn = 0; nn < 8; ++nn) {
        int c = nn * 16 + li;
#pragma unroll
        for (int q = 0; q < 4; ++q) {
            int rr = gr0 + q;
            if (rr < nrows)
                g16[(size_t)rr * 128 + c] = __float2half(acc[nn][q]);
        }
    }
}

// ---------- bin body: 2048 edges/block -> packed (row<<8 | node_in_bucket) ----------
__device__ __forceinline__ void bin_body(char* smem, int bb,
                                         const int* __restrict__ row,
                                         const int* __restrict__ col,
                                         int* __restrict__ gcur,
                                         uint32_t* __restrict__ binned,
                                         int E, int n, int nbuck) {
    int* hist = (int*)smem;
    int* base = (int*)(smem + 1024);
    int t = threadIdx.x;
    hist[t] = 0;
    __syncthreads();
    int e0 = bb * 2048 + t;
    int cc[8]; uint32_t pk[8];
#pragma unroll
    for (int i = 0; i < 8; ++i) {
        int e = e0 + i * 256;
        cc[i] = -1; pk[i] = 0;
        if (e < E) {
            int c = col[e];
            if ((unsigned)c < (unsigned)n) {
                cc[i] = c >> BSHIFT;
                pk[i] = ((uint32_t)row[e] << BSHIFT) | (uint32_t)(c & BMASK);
            }
        }
    }
#pragma unroll
    for (int i = 0; i < 8; ++i)
        if (cc[i] >= 0) atomicAdd(&hist[cc[i]], 1);
    __syncthreads();
    if (t < nbuck) {
        int h = hist[t];
        if (h) base[t] = atomicAdd(&gcur[t], h);
        hist[t] = 0;
    }
    __syncthreads();
#pragma unroll
    for (int i = 0; i < 8; ++i)
        if (cc[i] >= 0) {
            int b = cc[i];
            int p = base[b] + atomicAdd(&hist[b], 1);
            if (p < BCAP) binned[(size_t)b * BCAP + p] = pk[i];
        }
}

// ---------- fused kernel1: gemm1 blocks + bin blocks (disjoint roles, 32 KB LDS) ----------
__global__ __launch_bounds__(256) void gemm_bin_kernel(const float* __restrict__ src,
                                                       const __half* __restrict__ Wt,
                                                       __half* __restrict__ g16,
                                                       int nrows, int gblocks,
                                                       const int* __restrict__ row,
                                                       const int* __restrict__ col,
                                                       int* __restrict__ gcur,
                                                       uint32_t* __restrict__ binned,
                                                       int E, int n, int nbuck) {
    __shared__ char smem[32768];
    if ((int)blockIdx.x < gblocks)
        gemm1_body(smem, blockIdx.x, src, Wt, g16, nrows);
    else
        bin_body(smem, blockIdx.x - gblocks, row, col, gcur, binned, E, n, nbuck);
}

// ---------- gemm2: g2c[row] = half(dinv[row] * (act16[row] @ W)); compact rows ----------
__global__ __launch_bounds__(256) void gemm2_kernel(const __half* __restrict__ act16,
                                                    const __half* __restrict__ Wt,
                                                    const float* __restrict__ dinv,
                                                    __half* __restrict__ g16, int nrows) {
    __shared__ char smem[32768];
    _Float16* Bsw = (_Float16*)smem;
    stage_B(Bsw, Wt);

    int t = threadIdx.x;
    int w = t >> 6, lane = t & 63;
    int li = lane & 15, hg = lane >> 4;
    int r = blockIdx.x * 64 + w * 16 + li;
    int rc = r < nrows ? r : nrows - 1;
    const _Float16* xr = (const _Float16*)act16 + (size_t)rc * 128;

    f16x8 af[4];
#pragma unroll
    for (int kk = 0; kk < 4; ++kk)
        af[kk] = *(const f16x8*)(xr + kk * 32 + hg * 8);
    __syncthreads();

    f32x4 acc[8];
#pragma unroll
    for (int nn = 0; nn < 8; ++nn) acc[nn] = (f32x4)0.0f;
#pragma unroll
    for (int nn = 0; nn < 8; ++nn) {
        int c = nn * 16 + li;
        int cbase = c * 256;
        int sw = (c & 7) << 4;
#pragma unroll
        for (int kk = 0; kk < 4; ++kk) {
            f16x8 bf = *(const f16x8*)((const char*)Bsw + ((cbase + kk * 64 + hg * 16) ^ sw));
            acc[nn] = __builtin_amdgcn_mfma_f32_16x16x32_f16(af[kk], bf, acc[nn], 0, 0, 0);
        }
    }

    int gr0 = blockIdx.x * 64 + w * 16 + (hg << 2);
    float dv[4];
#pragma unroll
    for (int q = 0; q < 4; ++q) {
        int rr = gr0 + q;
        dv[q] = dinv[rr < nrows ? rr : 0];
    }
#pragma unroll
    for (int nn = 0; nn < 8; ++nn) {
        int c = nn * 16 + li;
#pragma unroll
        for (int q = 0; q < 4; ++q) {
            int rr = gr0 + q;
            if (rr < nrows)
                g16[(size_t)rr * 128 + c] = __float2half(acc[nn][q] * dv[q]);
        }
    }
}

// ---------- bucket: 1024 threads/block, per 256-node bucket -> off / dinv / csr ----------
__global__ __launch_bounds__(1024) void bucket_kernel(const uint32_t* __restrict__ binned,
                                                      const int* __restrict__ gcur,
                                                      int* __restrict__ off,
                                                      float* __restrict__ dinv,
                                                      int* __restrict__ csr,
                                                      int n, int nbuck) {
    __shared__ int wtot[4];
    __shared__ int sbase[256];
    __shared__ int hist[256];
    __shared__ int cur[256];
    int t = threadIdx.x;
    int lane = t & 63, w = t >> 6;
    int b = blockIdx.x;

    int v = 0, inc = 0;
    if (t < 256) {
        v = (t < nbuck) ? gcur[t] : 0;
        inc = v;
#pragma unroll
        for (int d = 1; d < 64; d <<= 1) { int u = __shfl_up(inc, d); if (lane >= d) inc += u; }
        if (lane == 63) wtot[w] = inc;
    }
    __syncthreads();
    if (t < 256) {
        int wb = 0;
        for (int i = 0; i < w; ++i) wb += wtot[i];
        sbase[t] = wb + inc - v;
    }
    __syncthreads();
    int base_b = sbase[b];
    int c_b    = gcur[b];

    if (t < 256) hist[t] = 0;
    __syncthreads();
    const uint32_t* reg = binned + (size_t)b * BCAP;
    for (int j = t; j < c_b; j += 1024)
        atomicAdd(&hist[reg[j] & BMASK], 1);
    __syncthreads();

    int h = 0, inc2 = 0;
    if (t < 256) {
        h = hist[t];
        inc2 = h;
#pragma unroll
        for (int d = 1; d < 64; d <<= 1) { int u = __shfl_up(inc2, d); if (lane >= d) inc2 += u; }
        if (lane == 63) wtot[w] = inc2;
    }
    __syncthreads();
    if (t < 256) {
        int wb2 = 0;
        for (int i = 0; i < w; ++i) wb2 += wtot[i];
        int lo = wb2 + inc2 - h;
        int node = (b << BSHIFT) + t;
        if (node < n) {
            off[node]  = base_b + lo;
            dinv[node] = rsqrtf((float)(h + 1));   // +1: self-loop
        }
        cur[t] = base_b + lo;
    }
    if (b == nbuck - 1 && t == 0)
        off[n] = sbase[nbuck - 1] + gcur[nbuck - 1];
    __syncthreads();
    for (int j = t; j < c_b; j += 1024) {
        uint32_t pv = reg[j];
        int p = atomicAdd(&cur[pv & BMASK], 1);
        csr[p] = (int)(pv >> BSHIFT);
    }
}

// ---------- aggregation v3: one 16-lane GROUP per node; 8-deep staging halves ----------
// v[16] staging cost 64 VGPRs -> VGPR 80 -> 16 waves/CU cap (round 8). Two 8-deep
// halves (~32 VGPRs staging) + __launch_bounds__(256,8) target <=64 VGPR -> 32
// waves/CU: same in-flight bytes/CU (32x8 vs 16x16) but 2x independent chains to
// hide L3 latency. Identical per-node summation order (bit-identical results).
// PRE=0: weight = dinv[idx]; out = relu(di*(di*h_self + Σ w_e*h_e) + b)
// PRE=1: weight = 1;          out = relu(di*(g'_self + Σ g'_e) + b)
template<int OUT16, int PRE>
__global__ __launch_bounds__(256, 8) void agg_f16(const __half* __restrict__ gh,
                                                  const int* __restrict__ csr,
                                                  const int* __restrict__ off,
                                                  const float* __restrict__ dinv,
                                                  const f4* __restrict__ bias4,   // [32]
                                                  void* __restrict__ outp,
                                                  int n) {
    int wid  = (blockIdx.x * 256 + threadIdx.x) >> 6;
    int lane = threadIdx.x & 63;
    int g  = lane >> 4;
    int li = lane & 15;
    int gbase = lane & 48;                 // group's lane base for shfl

    int node = wid * 4 + g;
    bool valid = node < n;
    int nodeC = valid ? node : 0;
    float di = dinv[nodeC];

    float a[8];
    {
        f4 sv = ((const f4*)(gh + (size_t)nodeC * 128))[li];   // self row segment
        __half2* sh = (__half2*)&sv;
        float sc = PRE ? 1.0f : di;
#pragma unroll
        for (int i = 0; i < 4; ++i) {
            float2 f = __half22float2(sh[i]);
            a[2*i] = sc * f.x; a[2*i+1] = sc * f.y;
        }
    }

    int s = off[nodeC];
    int deg = valid ? (off[nodeC + 1] - s) : 0;

    for (int base = 0; __any(base < deg); base += 16) {
        int idx = 0; float wv = 0.0f;
        if (base + li < deg) {
            idx = csr[s + base + li];             // group-coalesced (16 entries)
            wv  = PRE ? 1.0f : dinv[idx];
        }
#pragma unroll
        for (int half = 0; half < 2; ++half) {
            int hb = half * 8;
            int rr[8];
#pragma unroll
            for (int t2 = 0; t2 < 8; ++t2) rr[t2] = __shfl(idx, gbase + hb + t2);
            f4 v[8];
#pragma unroll
            for (int t2 = 0; t2 < 8; ++t2)
                v[t2] = ((const f4*)(gh + (size_t)rr[t2] * 128))[li];   // 8 in flight
            if (PRE) {
                int rem = deg - base - hb;         // group-uniform
#pragma unroll
                for (int t2 = 0; t2 < 8; ++t2) {
                    float wt = (t2 < rem) ? 1.0f : 0.0f;
                    __half2* hv = (__half2*)&v[t2];
#pragma unroll
                    for (int i = 0; i < 4; ++i) {
                        float2 f = __half22float2(hv[i]);
                        a[2*i]   = fmaf(wt, f.x, a[2*i]);
                        a[2*i+1] = fmaf(wt, f.y, a[2*i+1]);
                    }
                }
            } else {
#pragma unroll
                for (int t2 = 0; t2 < 8; ++t2) {
                    float wt = __shfl(wv, gbase + hb + t2);
                    __half2* hv = (__half2*)&v[t2];
#pragma unroll
                    for (int i = 0; i < 4; ++i) {
                        float2 f = __half22float2(hv[i]);
                        a[2*i]   = fmaf(wt, f.x, a[2*i]);
                        a[2*i+1] = fmaf(wt, f.y, a[2*i+1]);
                    }
                }
            }
        }
    }

    if (valid) {
        f4 b0 = bias4[li * 2], b1v = bias4[li * 2 + 1];
        float o[8];
#pragma unroll
        for (int u = 0; u < 4; ++u) {
            o[u]     = fmaxf(fmaf(di, a[u],     b0[u]),  0.0f);
            o[4 + u] = fmaxf(fmaf(di, a[4 + u], b1v[u]), 0.0f);
        }
        if (OUT16) {
            f16x8 hv;
#pragma unroll
            for (int u = 0; u < 8; ++u) hv[u] = (_Float16)o[u];
            *(f16x8*)((_Float16*)outp + (size_t)node * 128 + li * 8) = hv;
        } else {
            f4 o0, o1;
#pragma unroll
            for (int u = 0; u < 4; ++u) { o0[u] = o[u]; o1[u] = o[4 + u]; }
            f4* out4 = (f4*)outp;
            out4[(size_t)node * 32 + li * 2]     = o0;
            out4[(size_t)node * 32 + li * 2 + 1] = o1;
        }
    }
}

// ---------- launch ----------
extern "C" void kernel_launch(void* const* d_in, const int* in_sizes, int n_in,
                              void* d_out, int out_size, void* d_ws, size_t ws_size,
                              hipStream_t stream) {
    float*       xbuf = (float*)d_in[0];        // fp32 input; later reused for compact g2
    const int*   ei   = (const int*)d_in[1];
    const float* W1   = (const float*)d_in[2];
    const float* b1   = (const float*)d_in[3];
    const float* W2   = (const float*)d_in[4];
    const float* b2   = (const float*)d_in[5];
    float*       out  = (float*)d_out;

    int N = in_sizes[0] / 128;
    int E = in_sizes[1] / 2;
    const int* row = ei;          // sources (x_j)
    const int* col = ei + E;      // targets (aggregate index)

    int nbuck = (N + 255) >> BSHIFT;   // 196 for N=50000

    auto align256 = [](size_t v) { return (v + 255) & ~(size_t)255; };
    char* ws = (char*)d_ws;
    size_t pos = 0;
    int*      off    = (int*)(ws + pos);      pos += align256((size_t)(N + 1) * 4);
    float*    dinv   = (float*)(ws + pos);    pos += align256((size_t)N * 4);
    int*      csr    = (int*)(ws + pos);      pos += align256((size_t)E * 4);
    int*      gcur   = (int*)(ws + pos);      pos += align256(256 * 4);
    uint32_t* binned = (uint32_t*)(ws + pos); pos += align256((size_t)nbuck * BCAP * 4);
    __half*   Wt1    = (__half*)(ws + pos);   pos += align256(128 * 128 * 2);
    __half*   Wt2    = (__half*)(ws + pos);   pos += align256(128 * 128 * 2);
    // total ~10 MB

    // buffer routing (all compact 256-B fp16 rows, nothing in-place):
    //   g1c   : d_out upper half (written by gemm1, read by agg1)
    //   act16 : d_out lower half (written by agg1, read by gemm2)
    //   g2c   : xbuf             (written by gemm2 after xbuf consumed by gemm1)
    //   final : d_out full       (written by agg2; g1c/act16 dead by then)
    __half* act16 = (__half*)out;
    __half* g1c   = (__half*)((char*)out + (size_t)N * 256);
    __half* g2c   = (__half*)xbuf;

    int binblocks = (E + 2047) / 2048;
    int gblocks   = (N + 63) / 64;
    int ablocks   = (N + 15) / 16;     // 16 nodes per block (group-per-node agg)

    // prep: zero gcur + transpose both W's (replaces memset)
    prep_kernel<<<17, 256, 0, stream>>>(W1, W2, Wt1, Wt2, gcur);
    // fused: gemm1 (graph-independent — dinv deferred to agg) + bin
    gemm_bin_kernel<<<gblocks + binblocks, 256, 0, stream>>>(xbuf, Wt1, g1c, N, gblocks,
                                                             row, col, gcur, binned,
                                                             E, N, nbuck);
    bucket_kernel<<<nbuck, 1024, 0, stream>>>(binned, gcur, off, dinv, csr, N, nbuck);

    // layer 1: act1 = relu(di*(di*h_self + Σ dv*h) + b1) -> fp16 compact (d_out lower)
    agg_f16<1, 0><<<ablocks, 256, 0, stream>>>(g1c, csr, off, dinv, (const f4*)b1, act16, N);
    // layer 2: g2' = fp16(dinv * (act1 @ W2)) -> xbuf (pre-scaled rows)
    gemm2_kernel<<<gblocks, 256, 0, stream>>>(act16, Wt2, dinv, g2c, N);
    // agg2: out = relu(di*(g'_self + Σ g'_e) + b2) — no per-edge dinv gather
    agg_f16<0, 1><<<ablocks, 256, 0, stream>>>(g2c, csr, off, dinv, (const f4*)b2, out, N);
}

// Round 11
// 182.331 us; speedup vs baseline: 1.0325x; 1.0325x over previous
//
#include <hip/hip_runtime.h>
#include <hip/hip_fp16.h>
#include <stdint.h>

typedef float f4 __attribute__((ext_vector_type(4)));
typedef float f32x4 __attribute__((ext_vector_type(4)));
typedef _Float16 f16x8 __attribute__((ext_vector_type(8)));

#define BSHIFT 8
#define BMASK  255
#define BCAP   8192   // edges per 256-node bucket (mean 4096 -> huge headroom)
#define GPAD   16     // gcur stride in ints: one counter per 64-B line (anti false-sharing)

// ---------- prep: zero padded gcur + transpose W1/W2 -> fp16 [c][k] ----------
__global__ __launch_bounds__(256) void prep_kernel(const float* __restrict__ W1,
                                                   const float* __restrict__ W2,
                                                   __half* __restrict__ Wt1,
                                                   __half* __restrict__ Wt2,
                                                   int* __restrict__ gcur) {
    int t = threadIdx.x, b = blockIdx.x;
    if (b == 0) {
#pragma unroll
        for (int i = 0; i < GPAD; ++i) gcur[i * 256 + t] = 0;
        return;
    }
    int wi = (b - 1) >> 3, bi = (b - 1) & 7;
    const f4* w4 = (const f4*)(wi ? W2 : W1);
    _Float16* dst = (_Float16*)(wi ? Wt2 : Wt1);
#pragma unroll
    for (int it = 0; it < 2; ++it) {
        int chunk = bi * 512 + it * 256 + t;      // f4 index into 128x128 W
        f4 v = w4[chunk];
        int k = chunk >> 5, c0 = (chunk << 2) & 127;
#pragma unroll
        for (int u = 0; u < 4; ++u)
            dst[(size_t)(c0 + u) * 128 + k] = (_Float16)v[u];
    }
}

// ---------- stage B (Wt fp16 [c][k]) into swizzled LDS: byte^=((c&7)<<4) ----------
__device__ __forceinline__ void stage_B(_Float16* Bsw, const __half* __restrict__ Wt) {
    int t = threadIdx.x;
    const f4* wsrc = (const f4*)Wt;
#pragma unroll
    for (int i = 0; i < 8; ++i) {
        int cb = i * 256 + t;
        f4 v = wsrc[cb];
        int lin = cb * 16;
        int c = cb >> 4;
        *(f4*)((char*)Bsw + (lin ^ ((c & 7) << 4))) = v;
    }
}

// ---------- gemm1 body: g1c[row] = half(x_f32[row] @ W); A in regs (hi+lo fp16) ----------
__device__ __forceinline__ void gemm1_body(char* smem, int blk,
                                           const float* __restrict__ src,
                                           const __half* __restrict__ Wt,
                                           __half* __restrict__ g16, int nrows) {
    _Float16* Bsw = (_Float16*)smem;   // 32 KB
    stage_B(Bsw, Wt);

    int t = threadIdx.x;
    int w = t >> 6, lane = t & 63;
    int li = lane & 15, hg = lane >> 4;
    int r = blk * 64 + w * 16 + li;
    int rc = r < nrows ? r : nrows - 1;
    const float* xr = src + (size_t)rc * 128;

    f16x8 af[4], al[4];
#pragma unroll
    for (int kk = 0; kk < 4; ++kk) {
        f4 v0 = *(const f4*)(xr + kk * 32 + hg * 8);
        f4 v1 = *(const f4*)(xr + kk * 32 + hg * 8 + 4);
#pragma unroll
        for (int u = 0; u < 4; ++u) {
            float a0 = v0[u]; _Float16 h0 = (_Float16)a0;
            af[kk][u] = h0;     al[kk][u]     = (_Float16)(a0 - (float)h0);
            float a1 = v1[u]; _Float16 h1 = (_Float16)a1;
            af[kk][u + 4] = h1; al[kk][u + 4] = (_Float16)(a1 - (float)h1);
        }
    }
    __syncthreads();   // B ready (A loads overlapped with B staging)

    f32x4 acc[8];
#pragma unroll
    for (int nn = 0; nn < 8; ++nn) acc[nn] = (f32x4)0.0f;
#pragma unroll
    for (int nn = 0; nn < 8; ++nn) {
        int c = nn * 16 + li;
        int cbase = c * 256;
        int sw = (c & 7) << 4;
#pragma unroll
        for (int kk = 0; kk < 4; ++kk) {
            f16x8 bf = *(const f16x8*)((const char*)Bsw + ((cbase + kk * 64 + hg * 16) ^ sw));
            acc[nn] = __builtin_amdgcn_mfma_f32_16x16x32_f16(af[kk], bf, acc[nn], 0, 0, 0);
            acc[nn] = __builtin_amdgcn_mfma_f32_16x16x32_f16(al[kk], bf, acc[nn], 0, 0, 0);
        }
    }

    // epilogue: C/D col = lane&15, row = (lane>>4)*4 + reg (m89); COMPACT 256-B rows
    int gr0 = blk * 64 + w * 16 + (hg << 2);
#pragma unroll
    for (int nn = 0; nn < 8; ++nn) {
        int c = nn * 16 + li;
#pragma unroll
        for (int q = 0; q < 4; ++q) {
            int rr = gr0 + q;
            if (rr < nrows)
                g16[(size_t)rr * 128 + c] = __float2half(acc[nn][q]);
        }
    }
}

// ---------- bin body: 4096 edges/block -> packed (row<<8 | node_in_bucket) ----------
__device__ __forceinline__ void bin_body(char* smem, int bb,
                                         const int* __restrict__ row,
                                         const int* __restrict__ col,
                                         int* __restrict__ gcur,
                                         uint32_t* __restrict__ binned,
                                         int E, int n, int nbuck) {
    int* hist = (int*)smem;
    int* base = (int*)(smem + 1024);
    int t = threadIdx.x;
    hist[t] = 0;
    __syncthreads();
    int e0 = bb * 4096 + t;
    int cc[16]; uint32_t pk[16];
#pragma unroll
    for (int i = 0; i < 16; ++i) {
        int e = e0 + i * 256;
        cc[i] = -1; pk[i] = 0;
        if (e < E) {
            int c = col[e];
            if ((unsigned)c < (unsigned)n) {
                cc[i] = c >> BSHIFT;
                pk[i] = ((uint32_t)row[e] << BSHIFT) | (uint32_t)(c & BMASK);
            }
        }
    }
#pragma unroll
    for (int i = 0; i < 16; ++i)
        if (cc[i] >= 0) atomicAdd(&hist[cc[i]], 1);
    __syncthreads();
    if (t < nbuck) {
        int h = hist[t];
        if (h) base[t] = atomicAdd(&gcur[t * GPAD], h);   // one counter per 64-B line
        hist[t] = 0;
    }
    __syncthreads();
#pragma unroll
    for (int i = 0; i < 16; ++i)
        if (cc[i] >= 0) {
            int b = cc[i];
            int p = base[b] + atomicAdd(&hist[b], 1);
            if (p < BCAP) binned[(size_t)b * BCAP + p] = pk[i];
        }
}

// ---------- fused kernel1: gemm1 blocks + bin blocks (disjoint roles, 32 KB LDS) ----------
__global__ __launch_bounds__(256) void gemm_bin_kernel(const float* __restrict__ src,
                                                       const __half* __restrict__ Wt,
                                                       __half* __restrict__ g16,
                                                       int nrows, int gblocks,
                                                       const int* __restrict__ row,
                                                       const int* __restrict__ col,
                                                       int* __restrict__ gcur,
                                                       uint32_t* __restrict__ binned,
                                                       int E, int n, int nbuck) {
    __shared__ char smem[32768];
    if ((int)blockIdx.x < gblocks)
        gemm1_body(smem, blockIdx.x, src, Wt, g16, nrows);
    else
        bin_body(smem, blockIdx.x - gblocks, row, col, gcur, binned, E, n, nbuck);
}

// ---------- gemm2: g2c[row] = half(dinv[row] * (act16[row] @ W)); compact rows ----------
__global__ __launch_bounds__(256) void gemm2_kernel(const __half* __restrict__ act16,
                                                    const __half* __restrict__ Wt,
                                                    const float* __restrict__ dinv,
                                                    __half* __restrict__ g16, int nrows) {
    __shared__ char smem[32768];
    _Float16* Bsw = (_Float16*)smem;
    stage_B(Bsw, Wt);

    int t = threadIdx.x;
    int w = t >> 6, lane = t & 63;
    int li = lane & 15, hg = lane >> 4;
    int r = blockIdx.x * 64 + w * 16 + li;
    int rc = r < nrows ? r : nrows - 1;
    const _Float16* xr = (const _Float16*)act16 + (size_t)rc * 128;

    f16x8 af[4];
#pragma unroll
    for (int kk = 0; kk < 4; ++kk)
        af[kk] = *(const f16x8*)(xr + kk * 32 + hg * 8);
    __syncthreads();

    f32x4 acc[8];
#pragma unroll
    for (int nn = 0; nn < 8; ++nn) acc[nn] = (f32x4)0.0f;
#pragma unroll
    for (int nn = 0; nn < 8; ++nn) {
        int c = nn * 16 + li;
        int cbase = c * 256;
        int sw = (c & 7) << 4;
#pragma unroll
        for (int kk = 0; kk < 4; ++kk) {
            f16x8 bf = *(const f16x8*)((const char*)Bsw + ((cbase + kk * 64 + hg * 16) ^ sw));
            acc[nn] = __builtin_amdgcn_mfma_f32_16x16x32_f16(af[kk], bf, acc[nn], 0, 0, 0);
        }
    }

    int gr0 = blockIdx.x * 64 + w * 16 + (hg << 2);
    float dv[4];
#pragma unroll
    for (int q = 0; q < 4; ++q) {
        int rr = gr0 + q;
        dv[q] = dinv[rr < nrows ? rr : 0];
    }
#pragma unroll
    for (int nn = 0; nn < 8; ++nn) {
        int c = nn * 16 + li;
#pragma unroll
        for (int q = 0; q < 4; ++q) {
            int rr = gr0 + q;
            if (rr < nrows)
                g16[(size_t)rr * 128 + c] = __float2half(acc[nn][q] * dv[q]);
        }
    }
}

// ---------- bucket: 1024 threads/block, per 256-node bucket -> off / dinv / csr ----------
__global__ __launch_bounds__(1024) void bucket_kernel(const uint32_t* __restrict__ binned,
                                                      const int* __restrict__ gcur,
                                                      int* __restrict__ off,
                                                      float* __restrict__ dinv,
                                                      int* __restrict__ csr,
                                                      int n, int nbuck) {
    __shared__ int wtot[4];
    __shared__ int sbase[256];
    __shared__ int hist[256];
    __shared__ int cur[256];
    int t = threadIdx.x;
    int lane = t & 63, w = t >> 6;
    int b = blockIdx.x;

    int v = 0, inc = 0;
    if (t < 256) {
        v = (t < nbuck) ? gcur[t * GPAD] : 0;
        inc = v;
#pragma unroll
        for (int d = 1; d < 64; d <<= 1) { int u = __shfl_up(inc, d); if (lane >= d) inc += u; }
        if (lane == 63) wtot[w] = inc;
    }
    __syncthreads();
    if (t < 256) {
        int wb = 0;
        for (int i = 0; i < w; ++i) wb += wtot[i];
        sbase[t] = wb + inc - v;
    }
    __syncthreads();
    int base_b = sbase[b];
    int c_b    = gcur[b * GPAD];

    if (t < 256) hist[t] = 0;
    __syncthreads();
    const uint32_t* reg = binned + (size_t)b * BCAP;
    for (int j = t; j < c_b; j += 1024)
        atomicAdd(&hist[reg[j] & BMASK], 1);
    __syncthreads();

    int h = 0, inc2 = 0;
    if (t < 256) {
        h = hist[t];
        inc2 = h;
#pragma unroll
        for (int d = 1; d < 64; d <<= 1) { int u = __shfl_up(inc2, d); if (lane >= d) inc2 += u; }
        if (lane == 63) wtot[w] = inc2;
    }
    __syncthreads();
    if (t < 256) {
        int wb2 = 0;
        for (int i = 0; i < w; ++i) wb2 += wtot[i];
        int lo = wb2 + inc2 - h;
        int node = (b << BSHIFT) + t;
        if (node < n) {
            off[node]  = base_b + lo;
            dinv[node] = rsqrtf((float)(h + 1));   // +1: self-loop
        }
        cur[t] = base_b + lo;
    }
    if (b == nbuck - 1 && t == 0)
        off[n] = sbase[nbuck - 1] + gcur[(nbuck - 1) * GPAD];
    __syncthreads();
    for (int j = t; j < c_b; j += 1024) {
        uint32_t pv = reg[j];
        int p = atomicAdd(&cur[pv & BMASK], 1);
        csr[p] = (int)(pv >> BSHIFT);
    }
}

// ---------- aggregation (R8-best form): one 16-lane GROUP per node, 16-deep gathers ----------
// PRE=0: weight = dinv[idx]; out = relu(di*(di*h_self + Σ w_e*h_e) + b)
// PRE=1: weight = 1;          out = relu(di*(g'_self + Σ g'_e) + b)
template<int OUT16, int PRE>
__global__ __launch_bounds__(256) void agg_f16(const __half* __restrict__ gh,
                                               const int* __restrict__ csr,
                                               const int* __restrict__ off,
                                               const float* __restrict__ dinv,
                                               const f4* __restrict__ bias4,   // [32]
                                               void* __restrict__ outp,
                                               int n) {
    int wid  = (blockIdx.x * 256 + threadIdx.x) >> 6;
    int lane = threadIdx.x & 63;
    int g  = lane >> 4;
    int li = lane & 15;
    int gbase = lane & 48;                 // group's lane base for shfl

    int node = wid * 4 + g;
    bool valid = node < n;
    int nodeC = valid ? node : 0;
    float di = dinv[nodeC];

    float a[8];
    {
        f4 sv = ((const f4*)(gh + (size_t)nodeC * 128))[li];   // self row segment
        __half2* sh = (__half2*)&sv;
        float sc = PRE ? 1.0f : di;
#pragma unroll
        for (int i = 0; i < 4; ++i) {
            float2 f = __half22float2(sh[i]);
            a[2*i] = sc * f.x; a[2*i+1] = sc * f.y;
        }
    }

    int s = off[nodeC];
    int deg = valid ? (off[nodeC + 1] - s) : 0;

    for (int base = 0; __any(base < deg); base += 16) {
        int idx = 0; float wv = 0.0f;
        if (base + li < deg) {
            idx = csr[s + base + li];             // group-coalesced (16 entries)
            wv  = PRE ? 1.0f : dinv[idx];
        }
        int rr[16];
#pragma unroll
        for (int t2 = 0; t2 < 16; ++t2) rr[t2] = __shfl(idx, gbase + t2);
        f4 v[16];
#pragma unroll
        for (int t2 = 0; t2 < 16; ++t2)
            v[t2] = ((const f4*)(gh + (size_t)rr[t2] * 128))[li];   // 16 gathers in flight
        if (PRE) {
            int rem = deg - base;                  // group-uniform
#pragma unroll
            for (int t2 = 0; t2 < 16; ++t2) {
                float wt = (t2 < rem) ? 1.0f : 0.0f;
                __half2* hv = (__half2*)&v[t2];
#pragma unroll
                for (int i = 0; i < 4; ++i) {
                    float2 f = __half22float2(hv[i]);
                    a[2*i]   = fmaf(wt, f.x, a[2*i]);
                    a[2*i+1] = fmaf(wt, f.y, a[2*i+1]);
                }
            }
        } else {
#pragma unroll
            for (int t2 = 0; t2 < 16; ++t2) {
                float wt = __shfl(wv, gbase + t2);
                __half2* hv = (__half2*)&v[t2];
#pragma unroll
                for (int i = 0; i < 4; ++i) {
                    float2 f = __half22float2(hv[i]);
                    a[2*i]   = fmaf(wt, f.x, a[2*i]);
                    a[2*i+1] = fmaf(wt, f.y, a[2*i+1]);
                }
            }
        }
    }

    if (valid) {
        f4 b0 = bias4[li * 2], b1v = bias4[li * 2 + 1];
        float o[8];
#pragma unroll
        for (int u = 0; u < 4; ++u) {
            o[u]     = fmaxf(fmaf(di, a[u],     b0[u]),  0.0f);
            o[4 + u] = fmaxf(fmaf(di, a[4 + u], b1v[u]), 0.0f);
        }
        if (OUT16) {
            f16x8 hv;
#pragma unroll
            for (int u = 0; u < 8; ++u) hv[u] = (_Float16)o[u];
            *(f16x8*)((_Float16*)outp + (size_t)node * 128 + li * 8) = hv;
        } else {
            f4 o0, o1;
#pragma unroll
            for (int u = 0; u < 4; ++u) { o0[u] = o[u]; o1[u] = o[4 + u]; }
            f4* out4 = (f4*)outp;
            out4[(size_t)node * 32 + li * 2]     = o0;
            out4[(size_t)node * 32 + li * 2 + 1] = o1;
        }
    }
}

// ---------- launch ----------
extern "C" void kernel_launch(void* const* d_in, const int* in_sizes, int n_in,
                              void* d_out, int out_size, void* d_ws, size_t ws_size,
                              hipStream_t stream) {
    float*       xbuf = (float*)d_in[0];        // fp32 input; later reused for compact g2
    const int*   ei   = (const int*)d_in[1];
    const float* W1   = (const float*)d_in[2];
    const float* b1   = (const float*)d_in[3];
    const float* W2   = (const float*)d_in[4];
    const float* b2   = (const float*)d_in[5];
    float*       out  = (float*)d_out;

    int N = in_sizes[0] / 128;
    int E = in_sizes[1] / 2;
    const int* row = ei;          // sources (x_j)
    const int* col = ei + E;      // targets (aggregate index)

    int nbuck = (N + 255) >> BSHIFT;   // 196 for N=50000

    auto align256 = [](size_t v) { return (v + 255) & ~(size_t)255; };
    char* ws = (char*)d_ws;
    size_t pos = 0;
    int*      off    = (int*)(ws + pos);      pos += align256((size_t)(N + 1) * 4);
    float*    dinv   = (float*)(ws + pos);    pos += align256((size_t)N * 4);
    int*      csr    = (int*)(ws + pos);      pos += align256((size_t)E * 4);
    int*      gcur   = (int*)(ws + pos);      pos += align256(256 * GPAD * 4);  // padded counters
    uint32_t* binned = (uint32_t*)(ws + pos); pos += align256((size_t)nbuck * BCAP * 4);
    __half*   Wt1    = (__half*)(ws + pos);   pos += align256(128 * 128 * 2);
    __half*   Wt2    = (__half*)(ws + pos);   pos += align256(128 * 128 * 2);
    // total ~10 MB

    // buffer routing (all compact 256-B fp16 rows, nothing in-place):
    //   g1c   : d_out upper half (written by gemm1, read by agg1)
    //   act16 : d_out lower half (written by agg1, read by gemm2)
    //   g2c   : xbuf             (written by gemm2 after xbuf consumed by gemm1)
    //   final : d_out full       (written by agg2; g1c/act16 dead by then)
    __half* act16 = (__half*)out;
    __half* g1c   = (__half*)((char*)out + (size_t)N * 256);
    __half* g2c   = (__half*)xbuf;

    int binblocks = (E + 4095) / 4096;
    int gblocks   = (N + 63) / 64;
    int ablocks   = (N + 15) / 16;     // 16 nodes per block (group-per-node agg)

    // prep: zero padded gcur + transpose both W's
    prep_kernel<<<17, 256, 0, stream>>>(W1, W2, Wt1, Wt2, gcur);
    // fused: gemm1 (graph-independent — dinv deferred to agg) + bin
    gemm_bin_kernel<<<gblocks + binblocks, 256, 0, stream>>>(xbuf, Wt1, g1c, N, gblocks,
                                                             row, col, gcur, binned,
                                                             E, N, nbuck);
    bucket_kernel<<<nbuck, 1024, 0, stream>>>(binned, gcur, off, dinv, csr, N, nbuck);

    // layer 1: act1 = relu(di*(di*h_self + Σ dv*h) + b1) -> fp16 compact (d_out lower)
    agg_f16<1, 0><<<ablocks, 256, 0, stream>>>(g1c, csr, off, dinv, (const f4*)b1, act16, N);
    // layer 2: g2' = fp16(dinv * (act1 @ W2)) -> xbuf (pre-scaled rows)
    gemm2_kernel<<<gblocks, 256, 0, stream>>>(act16, Wt2, dinv, g2c, N);
    // agg2: out = relu(di*(g'_self + Σ g'_e) + b2) — no per-edge dinv gather
    agg_f16<0, 1><<<ablocks, 256, 0, stream>>>(g2c, csr, off, dinv, (const f4*)b2, out, N);
}